// Round 1
// 320.812 us; speedup vs baseline: 1.0314x; 1.0314x over previous
//
#include <hip/hip_runtime.h>
#include <math.h>

#define BSZ 2
#define SEQ 2048
#define DIM 2048
#define NH 32
#define NKV 8
#define HD 64
#define KVDIM 512

typedef short short8 __attribute__((ext_vector_type(8)));
typedef short short4v __attribute__((ext_vector_type(4)));
typedef float f32x4 __attribute__((ext_vector_type(4)));
typedef int i32x4 __attribute__((ext_vector_type(4)));

__device__ __forceinline__ short fbf(float x) {
    unsigned u = __float_as_uint(x);
    u = (u + 0x7fffu + ((u >> 16) & 1u)) >> 16;   // RNE f32->bf16
    return (short)u;
}

#define AS1(p) ((const __attribute__((address_space(1))) void*)(p))
#define AS3(p) ((__attribute__((address_space(3))) void*)(p))

#if defined(__has_builtin)
#if __has_builtin(__builtin_amdgcn_permlane16_swap) && __has_builtin(__builtin_amdgcn_permlane32_swap)
#define HAVE_PERMLANE 1
#endif
#endif

// reduce max/sum over the quad chain {l15, l15+16, l15+32, l15+48}
__device__ __forceinline__ float redmax4(float x) {
#ifdef HAVE_PERMLANE
    {
        auto p = __builtin_amdgcn_permlane16_swap(__float_as_uint(x), __float_as_uint(x), false, false);
        x = fmaxf(__uint_as_float(p[0]), __uint_as_float(p[1]));
    }
    {
        auto p = __builtin_amdgcn_permlane32_swap(__float_as_uint(x), __float_as_uint(x), false, false);
        x = fmaxf(__uint_as_float(p[0]), __uint_as_float(p[1]));
    }
#else
    x = fmaxf(x, __shfl_xor(x, 16));
    x = fmaxf(x, __shfl_xor(x, 32));
#endif
    return x;
}
__device__ __forceinline__ float redsum4(float x) {
#ifdef HAVE_PERMLANE
    {
        auto p = __builtin_amdgcn_permlane16_swap(__float_as_uint(x), __float_as_uint(x), false, false);
        x = __uint_as_float(p[0]) + __uint_as_float(p[1]);
    }
    {
        auto p = __builtin_amdgcn_permlane32_swap(__float_as_uint(x), __float_as_uint(x), false, false);
        x = __uint_as_float(p[0]) + __uint_as_float(p[1]);
    }
#else
    x += __shfl_xor(x, 16);
    x += __shfl_xor(x, 32);
#endif
    return x;
}

// ---------------------------------------------------------------------------
// prep: all fp32->bf16 conversions in ONE kernel.
// ---------------------------------------------------------------------------
__global__ __launch_bounds__(256) void prep(const float* __restrict__ X,
                                            const float* __restrict__ Wq,
                                            const float* __restrict__ Wk,
                                            const float* __restrict__ Wv,
                                            const float* __restrict__ Wo,
                                            short* __restrict__ Xb,
                                            short* __restrict__ Wqkv,
                                            short* __restrict__ Wob) {
    int i = blockIdx.x * 256 + threadIdx.x;
    const float* src; short* dst; int j;
    if (i < 2097152)      { src = X;  dst = Xb;             j = i; }
    else if (i < 3145728) { src = Wq; dst = Wqkv;           j = i - 2097152; }
    else if (i < 3407872) { src = Wk; dst = Wqkv + 4194304; j = i - 3145728; }
    else if (i < 3670016) { src = Wv; dst = Wqkv + 5242880; j = i - 3407872; }
    else                  { src = Wo; dst = Wob;            j = i - 3670016; }
    float4 f = ((const float4*)src)[j];
    short4v s = { fbf(f.x), fbf(f.y), fbf(f.z), fbf(f.w) };
    ((short4v*)dst)[j] = s;
}

// ---------------------------------------------------------------------------
// Fused QKV GEMM: C = Xb * Wqkv^T  (M=4096, N=3072, K=2048), m97-style
// K-loop. Epilogue:
//   cols [0,2048):    RoPE+qscale -> Qo bf16 [B,S,32,64]  (LDS-coalesced)
//   cols [2048,2560): RoPE        -> Ko bf16 [B,S,8,64]   (LDS-coalesced)
//   cols [2560,3072): transpose + PV k-permutation -> Vo bf16 [B,8,64,2048]
// ---------------------------------------------------------------------------
__global__ __launch_bounds__(256) void gemm_qkv(const short* __restrict__ A,
                                                const short* __restrict__ W,
                                                const float* __restrict__ cosT,
                                                const float* __restrict__ sinT,
                                                short* __restrict__ Qo,
                                                short* __restrict__ Ko,
                                                short* __restrict__ Vo) {
    __shared__ short SM[2 * 128 * 64];
    short* As = SM;
    short* Bs = SM + 128 * 64;
    const int K = 2048;
    const int tid = threadIdx.x;
    const int lane = tid & 63, wave = tid >> 6;
    const int l15 = lane & 15, quad = lane >> 4;
    const int m0 = blockIdx.y * 128, n0 = blockIdx.x * 128;
    const int wm = (wave >> 1) * 64, wn = (wave & 1) * 64;
    f32x4 acc[4][4] = {};
    int srow[4], gcol[4];
#pragma unroll
    for (int v = 0; v < 4; ++v) {
        int s = v * 256 + tid;
        srow[v] = s >> 3;
        gcol[v] = ((s & 7) ^ (srow[v] & 7)) * 8;
    }
    for (int kb = 0; kb < K; kb += 64) {
        __syncthreads();
#pragma unroll
        for (int v = 0; v < 4; ++v) {
            int s = v * 256 + tid;
            __builtin_amdgcn_global_load_lds(AS1(A + (size_t)(m0 + srow[v]) * K + kb + gcol[v]),
                                             AS3(&As[s * 8]), 16, 0, 0);
            __builtin_amdgcn_global_load_lds(AS1(W + (size_t)(n0 + srow[v]) * K + kb + gcol[v]),
                                             AS3(&Bs[s * 8]), 16, 0, 0);
        }
        __syncthreads();
#pragma unroll
        for (int kh = 0; kh < 2; ++kh) {
            const int cs = ((kh * 4 + quad) ^ (l15 & 7)) * 8;
            short8 af[4], bf8[4];
#pragma unroll
            for (int i = 0; i < 4; ++i)
                af[i] = *(const short8*)&As[(wm + i * 16 + l15) * 64 + cs];
#pragma unroll
            for (int j = 0; j < 4; ++j)
                bf8[j] = *(const short8*)&Bs[(wn + j * 16 + l15) * 64 + cs];
#pragma unroll
            for (int i = 0; i < 4; ++i)
#pragma unroll
                for (int j = 0; j < 4; ++j)
                    acc[i][j] = __builtin_amdgcn_mfma_f32_16x16x32_bf16(af[i], bf8[j], acc[i][j], 0, 0, 0);
        }
    }
    __syncthreads();                          // LDS free for epilogue reuse
    const int n0r = n0 + wn;
    if (n0r < 2560) {                         // Q or K: RoPE -> LDS -> 16B stores
        short* dst; int heads, hh; float scale;
        if (n0r < 2048) { dst = Qo; heads = NH;  hh = n0r >> 6;          scale = 0.125f * 1.44269504088896f; }
        else            { dst = Ko; heads = NKV; hh = (n0r - 2048) >> 6; scale = 1.0f; }
        short* EB = SM + wave * 4096;         // 64 rows x 64 cols per wave
#pragma unroll
        for (int i = 0; i < 4; ++i)
#pragma unroll
            for (int r = 0; r < 4; ++r) {
                int rr = i * 16 + quad * 4 + r;
                int s = (m0 + wm + rr) & (SEQ - 1);
                int msk = ((rr >> 1) & 7) * 8;
#pragma unroll
                for (int jp = 0; jp < 2; ++jp) {
                    int d1 = jp * 16 + l15;
                    float c1 = cosT[s * HD + d1], s1v = sinT[s * HD + d1];
                    float x1 = acc[i][jp][r], x2 = acc[i][jp + 2][r];
                    EB[rr * 64 + (d1 ^ msk)]        = fbf((x1 * c1 - x2 * s1v) * scale);
                    EB[rr * 64 + ((d1 + 32) ^ msk)] = fbf((x2 * c1 + x1 * s1v) * scale);
                }
            }
#pragma unroll
        for (int t = 0; t < 8; ++t) {
            int rr = (lane >> 3) + t * 8;
            int c = lane & 7;
            short8 v8 = *(const short8*)&EB[rr * 64 + c * 8];
            int dchunk = c ^ ((rr >> 1) & 7);
            int mrow = m0 + wm + rr;
            int s = mrow & (SEQ - 1), bb = mrow >> 11;
            *(short8*)&dst[((size_t)(bb * SEQ + s) * heads + hh) * HD + dchunk * 8] = v8;
        }
    } else {                                  // V: transposed + k-permuted
        const int hh = (n0r - 2560) >> 6;
#pragma unroll
        for (int i = 0; i < 4; ++i) {
            int mrow4 = m0 + wm + i * 16 + quad * 4;
            int s_abs = mrow4 & (SEQ - 1);
            int bb = mrow4 >> 11;
            int blk = s_abs >> 6, kk = s_abs & 63;   // kk multiple of 4
            int ob = ((kk >> 5) << 3) | (((kk >> 2) & 3) << 1) | ((kk >> 4) & 1);
#pragma unroll
            for (int j = 0; j < 4; ++j) {
                int d = j * 16 + l15;
                short4v pk = { fbf(acc[i][j][0]), fbf(acc[i][j][1]),
                               fbf(acc[i][j][2]), fbf(acc[i][j][3]) };
                *(short4v*)&Vo[(((size_t)(bb * NKV + hh) * HD + d) * SEQ) + blk * 64 + ob * 4] = pk;
            }
        }
    }
}

// ---------------------------------------------------------------------------
// bf16 NT GEMM (m97-style), fp32 C out — used for the Wo projection.
// ---------------------------------------------------------------------------
__global__ __launch_bounds__(256) void gemm_bf16(const short* __restrict__ A,
                                                 const short* __restrict__ W,
                                                 float* __restrict__ C,
                                                 int M, int N, int K) {
    __shared__ short As[128 * 64];
    __shared__ short Bs[128 * 64];
    const int tid = threadIdx.x;
    const int lane = tid & 63, wave = tid >> 6;
    const int l15 = lane & 15, quad = lane >> 4;
    const int m0 = blockIdx.y * 128, n0 = blockIdx.x * 128;
    const int wm = (wave >> 1) * 64, wn = (wave & 1) * 64;
    f32x4 acc[4][4] = {};
    int srow[4], gcol[4];
#pragma unroll
    for (int v = 0; v < 4; ++v) {
        int s = v * 256 + tid;
        srow[v] = s >> 3;
        gcol[v] = ((s & 7) ^ (srow[v] & 7)) * 8;
    }
    for (int kb = 0; kb < K; kb += 64) {
        __syncthreads();
#pragma unroll
        for (int v = 0; v < 4; ++v) {
            int s = v * 256 + tid;
            __builtin_amdgcn_global_load_lds(AS1(A + (size_t)(m0 + srow[v]) * K + kb + gcol[v]),
                                             AS3(&As[s * 8]), 16, 0, 0);
            __builtin_amdgcn_global_load_lds(AS1(W + (size_t)(n0 + srow[v]) * K + kb + gcol[v]),
                                             AS3(&Bs[s * 8]), 16, 0, 0);
        }
        __syncthreads();
#pragma unroll
        for (int kh = 0; kh < 2; ++kh) {
            const int cs = ((kh * 4 + quad) ^ (l15 & 7)) * 8;
            short8 af[4], bf8[4];
#pragma unroll
            for (int i = 0; i < 4; ++i)
                af[i] = *(const short8*)&As[(wm + i * 16 + l15) * 64 + cs];
#pragma unroll
            for (int j = 0; j < 4; ++j)
                bf8[j] = *(const short8*)&Bs[(wn + j * 16 + l15) * 64 + cs];
#pragma unroll
            for (int i = 0; i < 4; ++i)
#pragma unroll
                for (int j = 0; j < 4; ++j)
                    acc[i][j] = __builtin_amdgcn_mfma_f32_16x16x32_bf16(af[i], bf8[j], acc[i][j], 0, 0, 0);
        }
    }
#pragma unroll
    for (int i = 0; i < 4; ++i)
#pragma unroll
        for (int j = 0; j < 4; ++j)
#pragma unroll
            for (int r = 0; r < 4; ++r)
                C[(size_t)(m0 + wm + i * 16 + quad * 4 + r) * N + n0 + wn + j * 16 + l15] = acc[i][j][r];
}

// ---------------------------------------------------------------------------
// flash4 v2: 512 threads (8 waves), 256 q-rows per block, BK=128, same 64 KB
// double-buffered LDS -> 2 blocks/CU but 4 waves/SIMD (2x TLP vs v1).
//  - block remap pairs (bh, qt=k) with (bh, qt=7-k) on the same CU: constant
//    per-CU causal work (18 tile-units) + same-bh K/V L2 reuse.
//  - fully-masked (wave,g) sub-tiles skipped wave-uniformly (work conserved).
//  - softmax: max3 tree + permlane16/32_swap reduces (no lgkm stalls),
//    raw v_exp_f32, v_perm_b32 P->bf16 pair packing (identical rounding),
//    exact defer-rescale (al==1 -> skip O-rescale + alr broadcasts).
// ---------------------------------------------------------------------------
__global__ __launch_bounds__(512, 4) void flash4(const short* __restrict__ Qb,
                                                 const short* __restrict__ Kb,
                                                 const short* __restrict__ VT,
                                                 short* __restrict__ O) {
    __shared__ short Ks[2][128 * 64];
    __shared__ short Vs[2][64 * 128];
    const int d = blockIdx.x + blockIdx.y * 64;      // dispatch-linear id
    const int bh = (d & 255) >> 2;
    const int qt = (d < 256) ? 7 - (d & 3) : (d & 3);
    const int b = bh >> 5, h = bh & 31, kvh = h >> 2;
    const int tid = threadIdx.x;
    const int wave = tid >> 6, lane = tid & 63;
    const int l15 = lane & 15, quad = lane >> 4;

    short8 qf[2][2];
#pragma unroll
    for (int g = 0; g < 2; ++g) {
        const short* qp = Qb + ((size_t)b * SEQ + qt * 256 + g * 128 + wave * 16 + l15) * DIM + h * HD + quad * 8;
        qf[g][0] = *(const short8*)qp;
        qf[g][1] = *(const short8*)(qp + 32);
    }
    f32x4 o[2][4] = {};
    float m[2] = {-1e30f, -1e30f}, l[2] = {0.f, 0.f};

    const short* Kbase = Kb + (size_t)b * SEQ * KVDIM + kvh * HD;
    const short* Vbase = VT + (size_t)(b * NKV + kvh) * HD * SEQ;

    int krow[2], kcol[2], vrow[2], vcol[2];
#pragma unroll
    for (int v = 0; v < 2; ++v) {
        int s = v * 512 + tid;
        krow[v] = s >> 3;
        kcol[v] = ((s & 7) ^ (krow[v] & 7)) * 8;
        vrow[v] = s >> 4;
        vcol[v] = ((s & 15) ^ (vrow[v] & 7)) * 8;
    }
    auto issue = [&](int kt, int bi) {
#pragma unroll
        for (int v = 0; v < 2; ++v) {
            int s = v * 512 + tid;
            __builtin_amdgcn_global_load_lds(AS1(Kbase + (size_t)(kt * 128 + krow[v]) * KVDIM + kcol[v]),
                                             AS3(&Ks[bi][s * 8]), 16, 0, 0);
            __builtin_amdgcn_global_load_lds(AS1(Vbase + (size_t)vrow[v] * SEQ + kt * 128 + vcol[v]),
                                             AS3(&Vs[bi][s * 8]), 16, 0, 0);
        }
    };
    issue(0, 0);
    const int nkt = 2 * qt + 2;
    for (int kt = 0; kt < nkt; ++kt) {
        const int bi = kt & 1;
        __syncthreads();                        // drains prefetch for kt; prev compute done
        if (kt + 1 < nkt) issue(kt + 1, bi ^ 1);

#pragma unroll
        for (int g = 0; g < 2; ++g) {
            const int qmin = qt * 256 + g * 128 + wave * 16;
            if (kt * 128 > qmin + 15) continue;   // fully masked for this wave-row-block
            f32x4 st[8] = {};
#pragma unroll
            for (int kh = 0; kh < 2; ++kh) {
                const int cs = ((kh * 4 + quad) ^ (l15 & 7)) * 8;
#pragma unroll
                for (int nt = 0; nt < 8; ++nt) {
                    short8 ka = *(const short8*)&Ks[bi][(nt * 16 + l15) * 64 + cs];
                    st[nt] = __builtin_amdgcn_mfma_f32_16x16x32_bf16(ka, qf[g][kh], st[nt], 0, 0, 0);
                }
            }
            if (kt * 128 + 127 > qmin) {          // diagonal tile: causal mask
                const int q = qmin + l15;
#pragma unroll
                for (int nt = 0; nt < 8; ++nt)
                    if (kt * 128 + nt * 16 + 15 > qmin) {   // scalar-uniform guard
#pragma unroll
                        for (int r = 0; r < 4; ++r)
                            if (kt * 128 + nt * 16 + quad * 4 + r > q) st[nt][r] = -1e30f;
                    }
            }
            // tile max: max3-friendly tree, then cross-lane via permlane swaps
            float mnt[8];
#pragma unroll
            for (int nt = 0; nt < 8; ++nt)
                mnt[nt] = fmaxf(fmaxf(fmaxf(st[nt][0], st[nt][1]), st[nt][2]), st[nt][3]);
            float ma = fmaxf(fmaxf(mnt[0], mnt[1]), mnt[2]);
            float mb = fmaxf(fmaxf(mnt[3], mnt[4]), mnt[5]);
            float mc = fmaxf(fmaxf(mnt[6], mnt[7]), ma);
            float mx = redmax4(fmaxf(mb, mc));

            const bool noskip = !__all(mx <= m[g]);   // exact: skip only when al==1
            float mn = m[g];
            float al = 1.0f;
            float alr[4];
            if (noskip) {
                mn = fmaxf(m[g], mx);
                al = __builtin_amdgcn_exp2f(m[g] - mn);
                m[g] = mn;
#pragma unroll
                for (int r = 0; r < 4; ++r) alr[r] = __shfl(al, quad * 4 + r);  // hides under exp loop
            }
            i32x4 aw[4];                          // P as packed bf16 words (A-frags, k-permuted)
            f32x4 rs4 = {};
#pragma unroll
            for (int nt = 0; nt < 8; ++nt) {
                f32x4 pv;
#pragma unroll
                for (int r = 0; r < 4; ++r) pv[r] = __builtin_amdgcn_exp2f(st[nt][r] - mn);
                rs4 += pv;
                unsigned u0 = __float_as_uint(pv[0]) + 0x8000u;
                unsigned u1 = __float_as_uint(pv[1]) + 0x8000u;
                unsigned u2 = __float_as_uint(pv[2]) + 0x8000u;
                unsigned u3 = __float_as_uint(pv[3]) + 0x8000u;
                aw[nt >> 1][(nt & 1) * 2 + 0] = (int)__builtin_amdgcn_perm(u1, u0, 0x07060302u);
                aw[nt >> 1][(nt & 1) * 2 + 1] = (int)__builtin_amdgcn_perm(u3, u2, 0x07060302u);
            }
            float rs = redsum4((rs4[0] + rs4[1]) + (rs4[2] + rs4[3]));
            l[g] = l[g] * al + rs;
            if (noskip) {
#pragma unroll
                for (int dt = 0; dt < 4; ++dt) {
                    o[g][dt][0] *= alr[0]; o[g][dt][1] *= alr[1];
                    o[g][dt][2] *= alr[2]; o[g][dt][3] *= alr[3];
                }
            }
#pragma unroll
            for (int dt = 0; dt < 4; ++dt) {
                f32x4 t = o[g][dt];
#pragma unroll
                for (int kh = 0; kh < 4; ++kh) {
                    const int slot = (kh * 4 + quad) ^ (l15 & 7);   // XOR flips low-3 only
                    short8 vf = *(const short8*)&Vs[bi][(dt * 16 + l15) * 128 + slot * 8];
                    t = __builtin_amdgcn_mfma_f32_16x16x32_bf16(__builtin_bit_cast(short8, aw[kh]), vf, t, 0, 0, 0);
                }
                o[g][dt] = t;
            }
        }
    }
#pragma unroll
    for (int g = 0; g < 2; ++g) {
        float li = 1.0f / l[g];
        float lr[4];
#pragma unroll
        for (int r = 0; r < 4; ++r) lr[r] = __shfl(li, quad * 4 + r);
        short* Oo = O + ((size_t)b * SEQ + qt * 256 + g * 128 + wave * 16 + quad * 4) * DIM + h * HD + l15;
#pragma unroll
        for (int r = 0; r < 4; ++r)
#pragma unroll
            for (int dt = 0; dt < 4; ++dt)
                Oo[(size_t)r * DIM + dt * 16] = fbf(o[g][dt][r] * lr[r]);
    }
}

// ---------------------------------------------------------------------------
extern "C" void kernel_launch(void* const* d_in, const int* in_sizes, int n_in,
                              void* d_out, int out_size, void* d_ws, size_t ws_size,
                              hipStream_t stream) {
    const float* X    = (const float*)d_in[0];
    const float* cosT = (const float*)d_in[2];
    const float* sinT = (const float*)d_in[3];
    const float* Wq   = (const float*)d_in[4];
    const float* Wk   = (const float*)d_in[5];
    const float* Wv   = (const float*)d_in[6];
    const float* Wo   = (const float*)d_in[7];

    char* ws = (char*)d_ws;
    short* Xb    = (short*)(ws);                  // 16.8 MB; ATTb aliases after QKV gemm
    short* ATTb  = Xb;
    short* WQKVb = (short*)(ws + 16777216);       // 12.6 MB
    short* Wob   = (short*)(ws + 29360128);       // 8.4 MB
    short* Qbb   = (short*)(ws + 37748736);       // 16.8 MB
    short* Kbb   = (short*)(ws + 54525952);       // 4.2 MB (B*S*KVDIM bf16)
    short* VTb   = (short*)(ws + 58720256);       // 4.2 MB (B*NKV*HD*SEQ bf16)

    const int M = BSZ * SEQ;
    dim3 blk(256);

    prep<<<dim3(18432), blk, 0, stream>>>(X, Wq, Wk, Wv, Wo, Xb, WQKVb, Wob);
    gemm_qkv<<<dim3(24, M / 128), blk, 0, stream>>>(Xb, WQKVb, cosT, sinT, Qbb, Kbb, VTb);
    flash4<<<dim3(64, 8), dim3(512), 0, stream>>>(Qbb, Kbb, VTb, ATTb);
    gemm_bf16<<<dim3(DIM / 128, M / 128), blk, 0, stream>>>(ATTb, Wob, (float*)d_out, M, DIM, DIM);
}

// Round 2
// 307.451 us; speedup vs baseline: 1.0762x; 1.0435x over previous
//
#include <hip/hip_runtime.h>
#include <math.h>

#define BSZ 2
#define SEQ 2048
#define DIM 2048
#define NH 32
#define NKV 8
#define HD 64
#define KVDIM 512

typedef short short8 __attribute__((ext_vector_type(8)));
typedef short short4v __attribute__((ext_vector_type(4)));
typedef float f32x4 __attribute__((ext_vector_type(4)));
typedef int i32x4 __attribute__((ext_vector_type(4)));

__device__ __forceinline__ short fbf(float x) {
    unsigned u = __float_as_uint(x);
    u = (u + 0x7fffu + ((u >> 16) & 1u)) >> 16;   // RNE f32->bf16
    return (short)u;
}

#define AS1(p) ((const __attribute__((address_space(1))) void*)(p))
#define AS3(p) ((__attribute__((address_space(3))) void*)(p))

#if defined(__has_builtin)
#if __has_builtin(__builtin_amdgcn_permlane16_swap) && __has_builtin(__builtin_amdgcn_permlane32_swap)
#define HAVE_PERMLANE 1
#endif
#endif

// reduce max/sum over the quad chain {l15, l15+16, l15+32, l15+48}
__device__ __forceinline__ float redmax4(float x) {
#ifdef HAVE_PERMLANE
    {
        auto p = __builtin_amdgcn_permlane16_swap(__float_as_uint(x), __float_as_uint(x), false, false);
        x = fmaxf(__uint_as_float(p[0]), __uint_as_float(p[1]));
    }
    {
        auto p = __builtin_amdgcn_permlane32_swap(__float_as_uint(x), __float_as_uint(x), false, false);
        x = fmaxf(__uint_as_float(p[0]), __uint_as_float(p[1]));
    }
#else
    x = fmaxf(x, __shfl_xor(x, 16));
    x = fmaxf(x, __shfl_xor(x, 32));
#endif
    return x;
}
__device__ __forceinline__ float redsum4(float x) {
#ifdef HAVE_PERMLANE
    {
        auto p = __builtin_amdgcn_permlane16_swap(__float_as_uint(x), __float_as_uint(x), false, false);
        x = __uint_as_float(p[0]) + __uint_as_float(p[1]);
    }
    {
        auto p = __builtin_amdgcn_permlane32_swap(__float_as_uint(x), __float_as_uint(x), false, false);
        x = __uint_as_float(p[0]) + __uint_as_float(p[1]);
    }
#else
    x += __shfl_xor(x, 16);
    x += __shfl_xor(x, 32);
#endif
    return x;
}

// ---------------------------------------------------------------------------
// prep: all fp32->bf16 conversions in ONE kernel.
// ---------------------------------------------------------------------------
__global__ __launch_bounds__(256) void prep(const float* __restrict__ X,
                                            const float* __restrict__ Wq,
                                            const float* __restrict__ Wk,
                                            const float* __restrict__ Wv,
                                            const float* __restrict__ Wo,
                                            short* __restrict__ Xb,
                                            short* __restrict__ Wqkv,
                                            short* __restrict__ Wob) {
    int i = blockIdx.x * 256 + threadIdx.x;
    const float* src; short* dst; int j;
    if (i < 2097152)      { src = X;  dst = Xb;             j = i; }
    else if (i < 3145728) { src = Wq; dst = Wqkv;           j = i - 2097152; }
    else if (i < 3407872) { src = Wk; dst = Wqkv + 4194304; j = i - 3145728; }
    else if (i < 3670016) { src = Wv; dst = Wqkv + 5242880; j = i - 3407872; }
    else                  { src = Wo; dst = Wob;            j = i - 3670016; }
    float4 f = ((const float4*)src)[j];
    short4v s = { fbf(f.x), fbf(f.y), fbf(f.z), fbf(f.w) };
    ((short4v*)dst)[j] = s;
}

// ---------------------------------------------------------------------------
// Fused QKV GEMM v2: C = Xb * Wqkv^T  (M=4096, N=3072, K=2048).
// 256x256 tile, 512 thr (8 waves 2Mx4N, wave tile 128x64), BK=32,
// 4-deep LDS ring (4 x 32KB = 128KB), stage t+3 during tile t,
// COUNTED s_waitcnt vmcnt(8) + raw s_barrier (never drains to 0 in
// steady state -> loads stay in flight across barriers, T4).
// LDS layout per 256x32 tile: 16B slot s <-> (row,c8chunk) via
//   pair=row>>1, slot = pair*8 + (((c ^ (pair&3))<<1) | (row&1))
// -> conflict-free ds_read_b128 per aligned 8-lane group (T2).
// Grid 192 = 8 XCD * 24, bijective swizzle (T1): 2 A-panels per XCD.
// Epilogue identical to v1 (RoPE+qscale Q/K via per-wave LDS stage;
// V transpose + PV k-permutation), extended to the 128x64 wave tile.
// ---------------------------------------------------------------------------
__global__ __launch_bounds__(512, 2) void gemm_qkv(const short* __restrict__ A,
                                                   const short* __restrict__ W,
                                                   const float* __restrict__ cosT,
                                                   const float* __restrict__ sinT,
                                                   short* __restrict__ Qo,
                                                   short* __restrict__ Ko,
                                                   short* __restrict__ Vo) {
    __shared__ short SM[65536];               // 128 KiB: A-ring [4][8192] | B-ring [4][8192]
    const int K = 2048;
    const int NT = 64;                        // K / 32
    const int tid = threadIdx.x;
    const int lane = tid & 63, wave = tid >> 6;
    const int l15 = lane & 15, quad = lane >> 4;
    const int wm = (wave >> 2) * 128;         // wave_m in {0,1} -> row base
    const int wn = (wave & 3) * 64;           // wave_n in {0..3} -> col base (= head span)
    const int orig = blockIdx.x;
    const int wgid = (orig & 7) * 24 + (orig >> 3);   // bijective XCD swizzle (192 = 8*24)
    const int by = wgid / 12, bx = wgid - by * 12;
    const int m0 = by * 256, n0 = bx * 256;

    // staging map: linear 16B slot s -> (row, chunk) of a 256x32 tile
    size_t aoff[2], boff[2]; int lslot[2];
#pragma unroll
    for (int v = 0; v < 2; ++v) {
        int s = v * 512 + tid;
        int pr = s >> 3, w = s & 7;
        int row = (pr << 1) | (w & 1);
        int c = (w >> 1) ^ (pr & 3);
        aoff[v] = (size_t)(m0 + row) * K + c * 8;
        boff[v] = (size_t)(n0 + row) * K + c * 8;
        lslot[v] = s * 8;
    }
    // per-lane read bases (inverse of the staging map)
    const int r0a = wm + l15;
    const int pa = r0a >> 1;
    const int slotA0 = pa * 8 + (((quad ^ (pa & 3)) << 1) | (r0a & 1));
    const int r0b = wn + l15;
    const int pb = r0b >> 1;
    const int slotB0 = pb * 8 + (((quad ^ (pb & 3)) << 1) | (r0b & 1));

    f32x4 acc[8][4] = {};

    auto issue = [&](int t) {
        const int kb = t * 32;
        short* Ad = SM + (t & 3) * 8192;
        short* Bd = SM + 32768 + (t & 3) * 8192;
#pragma unroll
        for (int v = 0; v < 2; ++v) {
            __builtin_amdgcn_global_load_lds(AS1(A + aoff[v] + kb), AS3(Ad + lslot[v]), 16, 0, 0);
            __builtin_amdgcn_global_load_lds(AS1(W + boff[v] + kb), AS3(Bd + lslot[v]), 16, 0, 0);
        }
    };
    issue(0); issue(1); issue(2);
    asm volatile("s_waitcnt vmcnt(8)" ::: "memory");   // tile 0 landed (8 newest = tiles 1,2)
    __builtin_amdgcn_s_barrier();
    asm volatile("" ::: "memory");
    __builtin_amdgcn_sched_barrier(0);

    for (int t = 0; t < NT; ++t) {
        if (t < NT - 3) issue(t + 3);
        const short* Ab = SM + (t & 3) * 8192;
        const short* Bb = SM + 32768 + (t & 3) * 8192;
        short8 af[8], bf8[4];
#pragma unroll
        for (int j = 0; j < 4; ++j)
            bf8[j] = *(const short8*)&Bb[(slotB0 + j * 64) * 8];
#pragma unroll
        for (int i = 0; i < 8; ++i)
            af[i] = *(const short8*)&Ab[(slotA0 + i * 64) * 8];
        __builtin_amdgcn_s_setprio(1);
#pragma unroll
        for (int i = 0; i < 8; ++i)
#pragma unroll
            for (int j = 0; j < 4; ++j)
                acc[i][j] = __builtin_amdgcn_mfma_f32_16x16x32_bf16(af[i], bf8[j], acc[i][j], 0, 0, 0);
        __builtin_amdgcn_s_setprio(0);
        // counted waits: outstanding = 4 loads per staged tile ahead; need t+1 complete
        if (t < NT - 3)       asm volatile("s_waitcnt vmcnt(8)" ::: "memory");
        else if (t == NT - 3) asm volatile("s_waitcnt vmcnt(4)" ::: "memory");
        else if (t == NT - 2) asm volatile("s_waitcnt vmcnt(0)" ::: "memory");
        __builtin_amdgcn_s_barrier();
        asm volatile("" ::: "memory");
        __builtin_amdgcn_sched_barrier(0);
    }

    // ----------------- epilogue (LDS free for per-wave reuse) -----------------
    const int n0r = n0 + wn;
    if (n0r < 2560) {                         // Q or K: RoPE -> LDS -> 16B stores
        short* dst; int heads, hh; float scale;
        if (n0r < 2048) { dst = Qo; heads = NH;  hh = n0r >> 6;          scale = 0.125f * 1.44269504088896f; }
        else            { dst = Ko; heads = NKV; hh = (n0r - 2048) >> 6; scale = 1.0f; }
        short* EB = SM + wave * 8192;         // 128 rows x 64 cols per wave
#pragma unroll
        for (int i = 0; i < 8; ++i)
#pragma unroll
            for (int r = 0; r < 4; ++r) {
                int rr = i * 16 + quad * 4 + r;
                int s = (m0 + wm + rr) & (SEQ - 1);
                int msk = ((rr >> 1) & 7) * 8;
#pragma unroll
                for (int jp = 0; jp < 2; ++jp) {
                    int d1 = jp * 16 + l15;
                    float c1 = cosT[s * HD + d1], s1v = sinT[s * HD + d1];
                    float x1 = acc[i][jp][r], x2 = acc[i][jp + 2][r];
                    EB[rr * 64 + (d1 ^ msk)]        = fbf((x1 * c1 - x2 * s1v) * scale);
                    EB[rr * 64 + ((d1 + 32) ^ msk)] = fbf((x2 * c1 + x1 * s1v) * scale);
                }
            }
#pragma unroll
        for (int t = 0; t < 16; ++t) {
            int rr = (lane >> 3) + t * 8;
            int c = lane & 7;
            short8 v8 = *(const short8*)&EB[rr * 64 + c * 8];
            int dchunk = c ^ ((rr >> 1) & 7);
            int mrow = m0 + wm + rr;
            int s = mrow & (SEQ - 1), bb = mrow >> 11;
            *(short8*)&dst[((size_t)(bb * SEQ + s) * heads + hh) * HD + dchunk * 8] = v8;
        }
    } else {                                  // V: transposed + k-permuted
        const int hh = (n0r - 2560) >> 6;
#pragma unroll
        for (int i = 0; i < 8; ++i) {
            int mrow4 = m0 + wm + i * 16 + quad * 4;
            int s_abs = mrow4 & (SEQ - 1);
            int bb = mrow4 >> 11;
            int blk = s_abs >> 6, kk = s_abs & 63;   // kk multiple of 4
            int ob = ((kk >> 5) << 3) | (((kk >> 2) & 3) << 1) | ((kk >> 4) & 1);
#pragma unroll
            for (int j = 0; j < 4; ++j) {
                int d = j * 16 + l15;
                short4v pk = { fbf(acc[i][j][0]), fbf(acc[i][j][1]),
                               fbf(acc[i][j][2]), fbf(acc[i][j][3]) };
                *(short4v*)&Vo[(((size_t)(bb * NKV + hh) * HD + d) * SEQ) + blk * 64 + ob * 4] = pk;
            }
        }
    }
}

// ---------------------------------------------------------------------------
// bf16 NT GEMM (m97-style), fp32 C out — used for the Wo projection.
// ---------------------------------------------------------------------------
__global__ __launch_bounds__(256) void gemm_bf16(const short* __restrict__ A,
                                                 const short* __restrict__ W,
                                                 float* __restrict__ C,
                                                 int M, int N, int K) {
    __shared__ short As[128 * 64];
    __shared__ short Bs[128 * 64];
    const int tid = threadIdx.x;
    const int lane = tid & 63, wave = tid >> 6;
    const int l15 = lane & 15, quad = lane >> 4;
    const int m0 = blockIdx.y * 128, n0 = blockIdx.x * 128;
    const int wm = (wave >> 1) * 64, wn = (wave & 1) * 64;
    f32x4 acc[4][4] = {};
    int srow[4], gcol[4];
#pragma unroll
    for (int v = 0; v < 4; ++v) {
        int s = v * 256 + tid;
        srow[v] = s >> 3;
        gcol[v] = ((s & 7) ^ (srow[v] & 7)) * 8;
    }
    for (int kb = 0; kb < K; kb += 64) {
        __syncthreads();
#pragma unroll
        for (int v = 0; v < 4; ++v) {
            int s = v * 256 + tid;
            __builtin_amdgcn_global_load_lds(AS1(A + (size_t)(m0 + srow[v]) * K + kb + gcol[v]),
                                             AS3(&As[s * 8]), 16, 0, 0);
            __builtin_amdgcn_global_load_lds(AS1(W + (size_t)(n0 + srow[v]) * K + kb + gcol[v]),
                                             AS3(&Bs[s * 8]), 16, 0, 0);
        }
        __syncthreads();
#pragma unroll
        for (int kh = 0; kh < 2; ++kh) {
            const int cs = ((kh * 4 + quad) ^ (l15 & 7)) * 8;
            short8 af[4], bf8[4];
#pragma unroll
            for (int i = 0; i < 4; ++i)
                af[i] = *(const short8*)&As[(wm + i * 16 + l15) * 64 + cs];
#pragma unroll
            for (int j = 0; j < 4; ++j)
                bf8[j] = *(const short8*)&Bs[(wn + j * 16 + l15) * 64 + cs];
#pragma unroll
            for (int i = 0; i < 4; ++i)
#pragma unroll
                for (int j = 0; j < 4; ++j)
                    acc[i][j] = __builtin_amdgcn_mfma_f32_16x16x32_bf16(af[i], bf8[j], acc[i][j], 0, 0, 0);
        }
    }
#pragma unroll
    for (int i = 0; i < 4; ++i)
#pragma unroll
        for (int j = 0; j < 4; ++j)
#pragma unroll
            for (int r = 0; r < 4; ++r)
                C[(size_t)(m0 + wm + i * 16 + quad * 4 + r) * N + n0 + wn + j * 16 + l15] = acc[i][j][r];
}

// ---------------------------------------------------------------------------
// flash4 v2: 512 threads (8 waves), 256 q-rows per block, BK=128, same 64 KB
// double-buffered LDS -> 2 blocks/CU but 4 waves/SIMD (2x TLP vs v1).
// ---------------------------------------------------------------------------
__global__ __launch_bounds__(512, 4) void flash4(const short* __restrict__ Qb,
                                                 const short* __restrict__ Kb,
                                                 const short* __restrict__ VT,
                                                 short* __restrict__ O) {
    __shared__ short Ks[2][128 * 64];
    __shared__ short Vs[2][64 * 128];
    const int d = blockIdx.x + blockIdx.y * 64;      // dispatch-linear id
    const int bh = (d & 255) >> 2;
    const int qt = (d < 256) ? 7 - (d & 3) : (d & 3);
    const int b = bh >> 5, h = bh & 31, kvh = h >> 2;
    const int tid = threadIdx.x;
    const int wave = tid >> 6, lane = tid & 63;
    const int l15 = lane & 15, quad = lane >> 4;

    short8 qf[2][2];
#pragma unroll
    for (int g = 0; g < 2; ++g) {
        const short* qp = Qb + ((size_t)b * SEQ + qt * 256 + g * 128 + wave * 16 + l15) * DIM + h * HD + quad * 8;
        qf[g][0] = *(const short8*)qp;
        qf[g][1] = *(const short8*)(qp + 32);
    }
    f32x4 o[2][4] = {};
    float m[2] = {-1e30f, -1e30f}, l[2] = {0.f, 0.f};

    const short* Kbase = Kb + (size_t)b * SEQ * KVDIM + kvh * HD;
    const short* Vbase = VT + (size_t)(b * NKV + kvh) * HD * SEQ;

    int krow[2], kcol[2], vrow[2], vcol[2];
#pragma unroll
    for (int v = 0; v < 2; ++v) {
        int s = v * 512 + tid;
        krow[v] = s >> 3;
        kcol[v] = ((s & 7) ^ (krow[v] & 7)) * 8;
        vrow[v] = s >> 4;
        vcol[v] = ((s & 15) ^ (vrow[v] & 7)) * 8;
    }
    auto issue = [&](int kt, int bi) {
#pragma unroll
        for (int v = 0; v < 2; ++v) {
            int s = v * 512 + tid;
            __builtin_amdgcn_global_load_lds(AS1(Kbase + (size_t)(kt * 128 + krow[v]) * KVDIM + kcol[v]),
                                             AS3(&Ks[bi][s * 8]), 16, 0, 0);
            __builtin_amdgcn_global_load_lds(AS1(Vbase + (size_t)vrow[v] * SEQ + kt * 128 + vcol[v]),
                                             AS3(&Vs[bi][s * 8]), 16, 0, 0);
        }
    };
    issue(0, 0);
    const int nkt = 2 * qt + 2;
    for (int kt = 0; kt < nkt; ++kt) {
        const int bi = kt & 1;
        __syncthreads();                        // drains prefetch for kt; prev compute done
        if (kt + 1 < nkt) issue(kt + 1, bi ^ 1);

#pragma unroll
        for (int g = 0; g < 2; ++g) {
            const int qmin = qt * 256 + g * 128 + wave * 16;
            if (kt * 128 > qmin + 15) continue;   // fully masked for this wave-row-block
            f32x4 st[8] = {};
#pragma unroll
            for (int kh = 0; kh < 2; ++kh) {
                const int cs = ((kh * 4 + quad) ^ (l15 & 7)) * 8;
#pragma unroll
                for (int nt = 0; nt < 8; ++nt) {
                    short8 ka = *(const short8*)&Ks[bi][(nt * 16 + l15) * 64 + cs];
                    st[nt] = __builtin_amdgcn_mfma_f32_16x16x32_bf16(ka, qf[g][kh], st[nt], 0, 0, 0);
                }
            }
            if (kt * 128 + 127 > qmin) {          // diagonal tile: causal mask
                const int q = qmin + l15;
#pragma unroll
                for (int nt = 0; nt < 8; ++nt)
                    if (kt * 128 + nt * 16 + 15 > qmin) {   // scalar-uniform guard
#pragma unroll
                        for (int r = 0; r < 4; ++r)
                            if (kt * 128 + nt * 16 + quad * 4 + r > q) st[nt][r] = -1e30f;
                    }
            }
            // tile max: max3-friendly tree, then cross-lane via permlane swaps
            float mnt[8];
#pragma unroll
            for (int nt = 0; nt < 8; ++nt)
                mnt[nt] = fmaxf(fmaxf(fmaxf(st[nt][0], st[nt][1]), st[nt][2]), st[nt][3]);
            float ma = fmaxf(fmaxf(mnt[0], mnt[1]), mnt[2]);
            float mb = fmaxf(fmaxf(mnt[3], mnt[4]), mnt[5]);
            float mc = fmaxf(fmaxf(mnt[6], mnt[7]), ma);
            float mx = redmax4(fmaxf(mb, mc));

            const bool noskip = !__all(mx <= m[g]);   // exact: skip only when al==1
            float mn = m[g];
            float al = 1.0f;
            float alr[4];
            if (noskip) {
                mn = fmaxf(m[g], mx);
                al = __builtin_amdgcn_exp2f(m[g] - mn);
                m[g] = mn;
#pragma unroll
                for (int r = 0; r < 4; ++r) alr[r] = __shfl(al, quad * 4 + r);  // hides under exp loop
            }
            i32x4 aw[4];                          // P as packed bf16 words (A-frags, k-permuted)
            f32x4 rs4 = {};
#pragma unroll
            for (int nt = 0; nt < 8; ++nt) {
                f32x4 pv;
#pragma unroll
                for (int r = 0; r < 4; ++r) pv[r] = __builtin_amdgcn_exp2f(st[nt][r] - mn);
                rs4 += pv;
                unsigned u0 = __float_as_uint(pv[0]) + 0x8000u;
                unsigned u1 = __float_as_uint(pv[1]) + 0x8000u;
                unsigned u2 = __float_as_uint(pv[2]) + 0x8000u;
                unsigned u3 = __float_as_uint(pv[3]) + 0x8000u;
                aw[nt >> 1][(nt & 1) * 2 + 0] = (int)__builtin_amdgcn_perm(u1, u0, 0x07060302u);
                aw[nt >> 1][(nt & 1) * 2 + 1] = (int)__builtin_amdgcn_perm(u3, u2, 0x07060302u);
            }
            float rs = redsum4((rs4[0] + rs4[1]) + (rs4[2] + rs4[3]));
            l[g] = l[g] * al + rs;
            if (noskip) {
#pragma unroll
                for (int dt = 0; dt < 4; ++dt) {
                    o[g][dt][0] *= alr[0]; o[g][dt][1] *= alr[1];
                    o[g][dt][2] *= alr[2]; o[g][dt][3] *= alr[3];
                }
            }
#pragma unroll
            for (int dt = 0; dt < 4; ++dt) {
                f32x4 t = o[g][dt];
#pragma unroll
                for (int kh = 0; kh < 4; ++kh) {
                    const int slot = (kh * 4 + quad) ^ (l15 & 7);   // XOR flips low-3 only
                    short8 vf = *(const short8*)&Vs[bi][(dt * 16 + l15) * 128 + slot * 8];
                    t = __builtin_amdgcn_mfma_f32_16x16x32_bf16(__builtin_bit_cast(short8, aw[kh]), vf, t, 0, 0, 0);
                }
                o[g][dt] = t;
            }
        }
    }
#pragma unroll
    for (int g = 0; g < 2; ++g) {
        float li = 1.0f / l[g];
        float lr[4];
#pragma unroll
        for (int r = 0; r < 4; ++r) lr[r] = __shfl(li, quad * 4 + r);
        short* Oo = O + ((size_t)b * SEQ + qt * 256 + g * 128 + wave * 16 + quad * 4) * DIM + h * HD + l15;
#pragma unroll
        for (int r = 0; r < 4; ++r)
#pragma unroll
            for (int dt = 0; dt < 4; ++dt)
                Oo[(size_t)r * DIM + dt * 16] = fbf(o[g][dt][r] * lr[r]);
    }
}

// ---------------------------------------------------------------------------
extern "C" void kernel_launch(void* const* d_in, const int* in_sizes, int n_in,
                              void* d_out, int out_size, void* d_ws, size_t ws_size,
                              hipStream_t stream) {
    const float* X    = (const float*)d_in[0];
    const float* cosT = (const float*)d_in[2];
    const float* sinT = (const float*)d_in[3];
    const float* Wq   = (const float*)d_in[4];
    const float* Wk   = (const float*)d_in[5];
    const float* Wv   = (const float*)d_in[6];
    const float* Wo   = (const float*)d_in[7];

    char* ws = (char*)d_ws;
    short* Xb    = (short*)(ws);                  // 16.8 MB; ATTb aliases after QKV gemm
    short* ATTb  = Xb;
    short* WQKVb = (short*)(ws + 16777216);       // 12.6 MB
    short* Wob   = (short*)(ws + 29360128);       // 8.4 MB
    short* Qbb   = (short*)(ws + 37748736);       // 16.8 MB
    short* Kbb   = (short*)(ws + 54525952);       // 4.2 MB (B*S*KVDIM bf16)
    short* VTb   = (short*)(ws + 58720256);       // 4.2 MB (B*NKV*HD*SEQ bf16)

    const int M = BSZ * SEQ;
    dim3 blk(256);

    prep<<<dim3(18432), blk, 0, stream>>>(X, Wq, Wk, Wv, Wo, Xb, WQKVb, Wob);
    gemm_qkv<<<dim3(192), dim3(512), 0, stream>>>(Xb, WQKVb, cosT, sinT, Qbb, Kbb, VTb);
    flash4<<<dim3(64, 8), dim3(512), 0, stream>>>(Qbb, Kbb, VTb, ATTb);
    gemm_bf16<<<dim3(DIM / 128, M / 128), blk, 0, stream>>>(ATTb, Wob, (float*)d_out, M, DIM, DIM);
}

// Round 3
// 291.076 us; speedup vs baseline: 1.1368x; 1.0563x over previous
//
#include <hip/hip_runtime.h>
#include <math.h>

#define BSZ 2
#define SEQ 2048
#define DIM 2048
#define NH 32
#define NKV 8
#define HD 64
#define KVDIM 512

typedef short short8 __attribute__((ext_vector_type(8)));
typedef short short4v __attribute__((ext_vector_type(4)));
typedef float f32x4 __attribute__((ext_vector_type(4)));
typedef int i32x4 __attribute__((ext_vector_type(4)));

__device__ __forceinline__ short fbf(float x) {
    unsigned u = __float_as_uint(x);
    u = (u + 0x7fffu + ((u >> 16) & 1u)) >> 16;   // RNE f32->bf16
    return (short)u;
}

#define AS1(p) ((const __attribute__((address_space(1))) void*)(p))
#define AS3(p) ((__attribute__((address_space(3))) void*)(p))

#if defined(__has_builtin)
#if __has_builtin(__builtin_amdgcn_permlane16_swap) && __has_builtin(__builtin_amdgcn_permlane32_swap)
#define HAVE_PERMLANE 1
#endif
#endif

__device__ __forceinline__ float redmax4(float x) {
#ifdef HAVE_PERMLANE
    {
        auto p = __builtin_amdgcn_permlane16_swap(__float_as_uint(x), __float_as_uint(x), false, false);
        x = fmaxf(__uint_as_float(p[0]), __uint_as_float(p[1]));
    }
    {
        auto p = __builtin_amdgcn_permlane32_swap(__float_as_uint(x), __float_as_uint(x), false, false);
        x = fmaxf(__uint_as_float(p[0]), __uint_as_float(p[1]));
    }
#else
    x = fmaxf(x, __shfl_xor(x, 16));
    x = fmaxf(x, __shfl_xor(x, 32));
#endif
    return x;
}
__device__ __forceinline__ float redsum4(float x) {
#ifdef HAVE_PERMLANE
    {
        auto p = __builtin_amdgcn_permlane16_swap(__float_as_uint(x), __float_as_uint(x), false, false);
        x = __uint_as_float(p[0]) + __uint_as_float(p[1]);
    }
    {
        auto p = __builtin_amdgcn_permlane32_swap(__float_as_uint(x), __float_as_uint(x), false, false);
        x = __uint_as_float(p[0]) + __uint_as_float(p[1]);
    }
#else
    x += __shfl_xor(x, 16);
    x += __shfl_xor(x, 32);
#endif
    return x;
}

// ---------------------------------------------------------------------------
// prep: all fp32->bf16 conversions in ONE kernel.
// ---------------------------------------------------------------------------
__global__ __launch_bounds__(256) void prep(const float* __restrict__ X,
                                            const float* __restrict__ Wq,
                                            const float* __restrict__ Wk,
                                            const float* __restrict__ Wv,
                                            const float* __restrict__ Wo,
                                            short* __restrict__ Xb,
                                            short* __restrict__ Wqkv,
                                            short* __restrict__ Wob) {
    int i = blockIdx.x * 256 + threadIdx.x;
    const float* src; short* dst; int j;
    if (i < 2097152)      { src = X;  dst = Xb;             j = i; }
    else if (i < 3145728) { src = Wq; dst = Wqkv;           j = i - 2097152; }
    else if (i < 3407872) { src = Wk; dst = Wqkv + 4194304; j = i - 3145728; }
    else if (i < 3670016) { src = Wv; dst = Wqkv + 5242880; j = i - 3407872; }
    else                  { src = Wo; dst = Wob;            j = i - 3670016; }
    float4 f = ((const float4*)src)[j];
    short4v s = { fbf(f.x), fbf(f.y), fbf(f.z), fbf(f.w) };
    ((short4v*)dst)[j] = s;
}

// ---------------------------------------------------------------------------
// Fused QKV GEMM v2 (unchanged): 256x256, BK=32, ring-4, counted vmcnt.
// ---------------------------------------------------------------------------
__global__ __launch_bounds__(512, 2) void gemm_qkv(const short* __restrict__ A,
                                                   const short* __restrict__ W,
                                                   const float* __restrict__ cosT,
                                                   const float* __restrict__ sinT,
                                                   short* __restrict__ Qo,
                                                   short* __restrict__ Ko,
                                                   short* __restrict__ Vo) {
    __shared__ short SM[65536];               // 128 KiB: A-ring [4][8192] | B-ring [4][8192]
    const int K = 2048;
    const int NT = 64;
    const int tid = threadIdx.x;
    const int lane = tid & 63, wave = tid >> 6;
    const int l15 = lane & 15, quad = lane >> 4;
    const int wm = (wave >> 2) * 128;
    const int wn = (wave & 3) * 64;
    const int orig = blockIdx.x;
    const int wgid = (orig & 7) * 24 + (orig >> 3);
    const int by = wgid / 12, bx = wgid - by * 12;
    const int m0 = by * 256, n0 = bx * 256;

    size_t aoff[2], boff[2]; int lslot[2];
#pragma unroll
    for (int v = 0; v < 2; ++v) {
        int s = v * 512 + tid;
        int pr = s >> 3, w = s & 7;
        int row = (pr << 1) | (w & 1);
        int c = (w >> 1) ^ (pr & 3);
        aoff[v] = (size_t)(m0 + row) * K + c * 8;
        boff[v] = (size_t)(n0 + row) * K + c * 8;
        lslot[v] = s * 8;
    }
    const int r0a = wm + l15;
    const int pa = r0a >> 1;
    const int slotA0 = pa * 8 + (((quad ^ (pa & 3)) << 1) | (r0a & 1));
    const int r0b = wn + l15;
    const int pb = r0b >> 1;
    const int slotB0 = pb * 8 + (((quad ^ (pb & 3)) << 1) | (r0b & 1));

    f32x4 acc[8][4] = {};

    auto issue = [&](int t) {
        const int kb = t * 32;
        short* Ad = SM + (t & 3) * 8192;
        short* Bd = SM + 32768 + (t & 3) * 8192;
#pragma unroll
        for (int v = 0; v < 2; ++v) {
            __builtin_amdgcn_global_load_lds(AS1(A + aoff[v] + kb), AS3(Ad + lslot[v]), 16, 0, 0);
            __builtin_amdgcn_global_load_lds(AS1(W + boff[v] + kb), AS3(Bd + lslot[v]), 16, 0, 0);
        }
    };
    issue(0); issue(1); issue(2);
    asm volatile("s_waitcnt vmcnt(8)" ::: "memory");
    __builtin_amdgcn_s_barrier();
    asm volatile("" ::: "memory");
    __builtin_amdgcn_sched_barrier(0);

    for (int t = 0; t < NT; ++t) {
        if (t < NT - 3) issue(t + 3);
        const short* Ab = SM + (t & 3) * 8192;
        const short* Bb = SM + 32768 + (t & 3) * 8192;
        short8 af[8], bf8[4];
#pragma unroll
        for (int j = 0; j < 4; ++j)
            bf8[j] = *(const short8*)&Bb[(slotB0 + j * 64) * 8];
#pragma unroll
        for (int i = 0; i < 8; ++i)
            af[i] = *(const short8*)&Ab[(slotA0 + i * 64) * 8];
        __builtin_amdgcn_s_setprio(1);
#pragma unroll
        for (int i = 0; i < 8; ++i)
#pragma unroll
            for (int j = 0; j < 4; ++j)
                acc[i][j] = __builtin_amdgcn_mfma_f32_16x16x32_bf16(af[i], bf8[j], acc[i][j], 0, 0, 0);
        __builtin_amdgcn_s_setprio(0);
        if (t < NT - 3)       asm volatile("s_waitcnt vmcnt(8)" ::: "memory");
        else if (t == NT - 3) asm volatile("s_waitcnt vmcnt(4)" ::: "memory");
        else if (t == NT - 2) asm volatile("s_waitcnt vmcnt(0)" ::: "memory");
        __builtin_amdgcn_s_barrier();
        asm volatile("" ::: "memory");
        __builtin_amdgcn_sched_barrier(0);
    }

    const int n0r = n0 + wn;
    if (n0r < 2560) {
        short* dst; int heads, hh; float scale;
        if (n0r < 2048) { dst = Qo; heads = NH;  hh = n0r >> 6;          scale = 0.125f * 1.44269504088896f; }
        else            { dst = Ko; heads = NKV; hh = (n0r - 2048) >> 6; scale = 1.0f; }
        short* EB = SM + wave * 8192;
#pragma unroll
        for (int i = 0; i < 8; ++i)
#pragma unroll
            for (int r = 0; r < 4; ++r) {
                int rr = i * 16 + quad * 4 + r;
                int s = (m0 + wm + rr) & (SEQ - 1);
                int msk = ((rr >> 1) & 7) * 8;
#pragma unroll
                for (int jp = 0; jp < 2; ++jp) {
                    int d1 = jp * 16 + l15;
                    float c1 = cosT[s * HD + d1], s1v = sinT[s * HD + d1];
                    float x1 = acc[i][jp][r], x2 = acc[i][jp + 2][r];
                    EB[rr * 64 + (d1 ^ msk)]        = fbf((x1 * c1 - x2 * s1v) * scale);
                    EB[rr * 64 + ((d1 + 32) ^ msk)] = fbf((x2 * c1 + x1 * s1v) * scale);
                }
            }
#pragma unroll
        for (int t = 0; t < 16; ++t) {
            int rr = (lane >> 3) + t * 8;
            int c = lane & 7;
            short8 v8 = *(const short8*)&EB[rr * 64 + c * 8];
            int dchunk = c ^ ((rr >> 1) & 7);
            int mrow = m0 + wm + rr;
            int s = mrow & (SEQ - 1), bb = mrow >> 11;
            *(short8*)&dst[((size_t)(bb * SEQ + s) * heads + hh) * HD + dchunk * 8] = v8;
        }
    } else {
        const int hh = (n0r - 2560) >> 6;
#pragma unroll
        for (int i = 0; i < 8; ++i) {
            int mrow4 = m0 + wm + i * 16 + quad * 4;
            int s_abs = mrow4 & (SEQ - 1);
            int bb = mrow4 >> 11;
            int blk = s_abs >> 6, kk = s_abs & 63;
            int ob = ((kk >> 5) << 3) | (((kk >> 2) & 3) << 1) | ((kk >> 4) & 1);
#pragma unroll
            for (int j = 0; j < 4; ++j) {
                int d = j * 16 + l15;
                short4v pk = { fbf(acc[i][j][0]), fbf(acc[i][j][1]),
                               fbf(acc[i][j][2]), fbf(acc[i][j][3]) };
                *(short4v*)&Vo[(((size_t)(bb * NKV + hh) * HD + d) * SEQ) + blk * 64 + ob * 4] = pk;
            }
        }
    }
}

// ---------------------------------------------------------------------------
// bf16 NT GEMM v2 (Wo projection): BM=256 x BN=128, ring-4, counted vmcnt,
// 8 waves 4Mx2N (wave 64x64), grid 256 = 1 block/CU, XCD-swizzled.
// ---------------------------------------------------------------------------
__global__ __launch_bounds__(512, 2) void gemm_bf16(const short* __restrict__ A,
                                                    const short* __restrict__ W,
                                                    float* __restrict__ C,
                                                    int M, int N, int K) {
    __shared__ short SM[49152];               // 96 KiB: A-ring [4][8192] | B-ring [4][4096]
    const int NT = K >> 5;
    const int tid = threadIdx.x;
    const int lane = tid & 63, wave = tid >> 6;
    const int l15 = lane & 15, quad = lane >> 4;
    const int wm = (wave >> 1) * 64;
    const int wn = (wave & 1) * 64;
    const int orig = blockIdx.x;
    const int wgid = (orig & 7) * 32 + (orig >> 3);
    const int by = wgid >> 4, bx = wgid & 15;
    const int m0 = by * 256, n0 = bx * 128;

    size_t aoff[2]; int lslotA[2];
#pragma unroll
    for (int v = 0; v < 2; ++v) {
        int s = v * 512 + tid;
        int pr = s >> 3, w = s & 7;
        int row = (pr << 1) | (w & 1);
        int c = (w >> 1) ^ (pr & 3);
        aoff[v] = (size_t)(m0 + row) * K + c * 8;
        lslotA[v] = s * 8;
    }
    size_t boff; int lslotB;
    {
        int s = tid;
        int pr = s >> 3, w = s & 7;
        int row = (pr << 1) | (w & 1);
        int c = (w >> 1) ^ (pr & 3);
        boff = (size_t)(n0 + row) * K + c * 8;
        lslotB = s * 8;
    }
    const int r0a = wm + l15;
    const int pa = r0a >> 1;
    const int slotA0 = pa * 8 + (((quad ^ (pa & 3)) << 1) | (r0a & 1));
    const int r0b = wn + l15;
    const int pb = r0b >> 1;
    const int slotB0 = pb * 8 + (((quad ^ (pb & 3)) << 1) | (r0b & 1));

    f32x4 acc[4][4] = {};

    auto issue = [&](int t) {
        const int kb = t * 32;
        short* Ad = SM + (t & 3) * 8192;
        short* Bd = SM + 32768 + (t & 3) * 4096;
#pragma unroll
        for (int v = 0; v < 2; ++v)
            __builtin_amdgcn_global_load_lds(AS1(A + aoff[v] + kb), AS3(Ad + lslotA[v]), 16, 0, 0);
        __builtin_amdgcn_global_load_lds(AS1(W + boff + kb), AS3(Bd + lslotB), 16, 0, 0);
    };
    issue(0); issue(1); issue(2);
    asm volatile("s_waitcnt vmcnt(6)" ::: "memory");
    __builtin_amdgcn_s_barrier();
    asm volatile("" ::: "memory");
    __builtin_amdgcn_sched_barrier(0);

    for (int t = 0; t < NT; ++t) {
        if (t < NT - 3) issue(t + 3);
        const short* Ab = SM + (t & 3) * 8192;
        const short* Bb = SM + 32768 + (t & 3) * 4096;
        short8 af[4], bf8[4];
#pragma unroll
        for (int j = 0; j < 4; ++j)
            bf8[j] = *(const short8*)&Bb[(slotB0 + j * 64) * 8];
#pragma unroll
        for (int i = 0; i < 4; ++i)
            af[i] = *(const short8*)&Ab[(slotA0 + i * 64) * 8];
        __builtin_amdgcn_s_setprio(1);
#pragma unroll
        for (int i = 0; i < 4; ++i)
#pragma unroll
            for (int j = 0; j < 4; ++j)
                acc[i][j] = __builtin_amdgcn_mfma_f32_16x16x32_bf16(af[i], bf8[j], acc[i][j], 0, 0, 0);
        __builtin_amdgcn_s_setprio(0);
        if (t < NT - 3)       asm volatile("s_waitcnt vmcnt(6)" ::: "memory");
        else if (t == NT - 3) asm volatile("s_waitcnt vmcnt(3)" ::: "memory");
        else if (t == NT - 2) asm volatile("s_waitcnt vmcnt(0)" ::: "memory");
        __builtin_amdgcn_s_barrier();
        asm volatile("" ::: "memory");
        __builtin_amdgcn_sched_barrier(0);
    }
#pragma unroll
    for (int i = 0; i < 4; ++i)
#pragma unroll
        for (int j = 0; j < 4; ++j)
#pragma unroll
            for (int r = 0; r < 4; ++r)
                C[(size_t)(m0 + wm + i * 16 + quad * 4 + r) * N + n0 + wn + j * 16 + l15] = acc[i][j][r];
}

// ---------------------------------------------------------------------------
// flash4 v3: BK=64, 128 q-rows/block (8 waves x 16 rows), 32 KiB LDS
// -> 4 blocks/CU = 32 waves/CU. Grid 1024, balanced qt remap. Counted
// vmcnt(2) + raw s_barrier. setprio around MFMA clusters.
// ---------------------------------------------------------------------------
__global__ __launch_bounds__(512, 4) void flash4(const short* __restrict__ Qb,
                                                 const short* __restrict__ Kb,
                                                 const short* __restrict__ VT,
                                                 short* __restrict__ O) {
    __shared__ short Ks[2][64 * 64];
    __shared__ short Vs[2][64 * 64];
    const int d = blockIdx.x;
    const int bh = (d & 511) >> 3;
    const int qt = (d < 512) ? 15 - (d & 7) : (d & 7);
    const int b = bh >> 5, h = bh & 31, kvh = h >> 2;
    const int tid = threadIdx.x;
    const int wave = tid >> 6, lane = tid & 63;
    const int l15 = lane & 15, quad = lane >> 4;

    const short* qp = Qb + ((size_t)b * SEQ + qt * 128 + wave * 16 + l15) * DIM + h * HD + quad * 8;
    short8 qf0 = *(const short8*)qp;
    short8 qf1 = *(const short8*)(qp + 32);

    f32x4 o[4] = {};
    float m = -1e30f, l = 0.f;

    const short* Kbase = Kb + (size_t)b * SEQ * KVDIM + kvh * HD;
    const short* Vbase = VT + (size_t)(b * NKV + kvh) * HD * SEQ;

    const int srow = tid >> 3;                       // 0..63 (K: key row, V: d row)
    const int scol = ((tid & 7) ^ (srow & 7)) * 8;   // swizzled 16B chunk
    auto issue = [&](int kt, int bi) {
        __builtin_amdgcn_global_load_lds(AS1(Kbase + (size_t)(kt * 64 + srow) * KVDIM + scol),
                                         AS3(&Ks[bi][tid * 8]), 16, 0, 0);
        __builtin_amdgcn_global_load_lds(AS1(Vbase + (size_t)srow * SEQ + kt * 64 + scol),
                                         AS3(&Vs[bi][tid * 8]), 16, 0, 0);
    };
    issue(0, 0);
    const int nkt = 2 * qt + 2;
    const int qmin = qt * 128 + wave * 16;
    for (int kt = 0; kt < nkt; ++kt) {
        const int bi = kt & 1;
        __builtin_amdgcn_s_barrier();                // all waves done with buffer bi^1
        asm volatile("" ::: "memory");
        if (kt + 1 < nkt) {
            issue(kt + 1, bi ^ 1);
            asm volatile("s_waitcnt vmcnt(2)" ::: "memory");   // tile kt landed
        } else {
            asm volatile("s_waitcnt vmcnt(0)" ::: "memory");
        }
        __builtin_amdgcn_sched_barrier(0);
        if (kt * 64 > qmin + 15) continue;           // fully masked (wave-uniform)

        f32x4 st[4] = {};
        __builtin_amdgcn_s_setprio(1);
#pragma unroll
        for (int kh = 0; kh < 2; ++kh) {
            const int cs = ((kh * 4 + quad) ^ (l15 & 7)) * 8;
#pragma unroll
            for (int nt = 0; nt < 4; ++nt) {
                short8 ka = *(const short8*)&Ks[bi][(nt * 16 + l15) * 64 + cs];
                st[nt] = __builtin_amdgcn_mfma_f32_16x16x32_bf16(ka, kh ? qf1 : qf0, st[nt], 0, 0, 0);
            }
        }
        __builtin_amdgcn_s_setprio(0);
        if (kt * 64 + 63 > qmin) {                   // diagonal tile: causal mask
            const int q = qmin + l15;
#pragma unroll
            for (int nt = 0; nt < 4; ++nt)
                if (kt * 64 + nt * 16 + 15 > qmin) {
#pragma unroll
                    for (int r = 0; r < 4; ++r)
                        if (kt * 64 + nt * 16 + quad * 4 + r > q) st[nt][r] = -1e30f;
                }
        }
        float mnt[4];
#pragma unroll
        for (int nt = 0; nt < 4; ++nt)
            mnt[nt] = fmaxf(fmaxf(fmaxf(st[nt][0], st[nt][1]), st[nt][2]), st[nt][3]);
        float mx = redmax4(fmaxf(fmaxf(mnt[0], mnt[1]), fmaxf(mnt[2], mnt[3])));

        const bool noskip = !__all(mx <= m);         // exact: skip only when al==1
        float mn = m;
        float al = 1.0f;
        float alr[4];
        if (noskip) {
            mn = fmaxf(m, mx);
            al = __builtin_amdgcn_exp2f(m - mn);
            m = mn;
#pragma unroll
            for (int r = 0; r < 4; ++r) alr[r] = __shfl(al, quad * 4 + r);
        }
        i32x4 aw[2];                                 // per kh: 4 packed bf16 words
        f32x4 rs4 = {};
#pragma unroll
        for (int nt = 0; nt < 4; ++nt) {
            f32x4 pv;
#pragma unroll
            for (int r = 0; r < 4; ++r) pv[r] = __builtin_amdgcn_exp2f(st[nt][r] - mn);
            rs4 += pv;
            unsigned u0 = __float_as_uint(pv[0]) + 0x8000u;
            unsigned u1 = __float_as_uint(pv[1]) + 0x8000u;
            unsigned u2 = __float_as_uint(pv[2]) + 0x8000u;
            unsigned u3 = __float_as_uint(pv[3]) + 0x8000u;
            aw[nt >> 1][(nt & 1) * 2 + 0] = (int)__builtin_amdgcn_perm(u1, u0, 0x07060302u);
            aw[nt >> 1][(nt & 1) * 2 + 1] = (int)__builtin_amdgcn_perm(u3, u2, 0x07060302u);
        }
        float rs = redsum4((rs4[0] + rs4[1]) + (rs4[2] + rs4[3]));
        l = l * al + rs;
        if (noskip) {
#pragma unroll
            for (int dt = 0; dt < 4; ++dt) {
                o[dt][0] *= alr[0]; o[dt][1] *= alr[1];
                o[dt][2] *= alr[2]; o[dt][3] *= alr[3];
            }
        }
        __builtin_amdgcn_s_setprio(1);
#pragma unroll
        for (int dt = 0; dt < 4; ++dt) {
            f32x4 t = o[dt];
#pragma unroll
            for (int kh = 0; kh < 2; ++kh) {
                const int slot = (kh * 4 + quad) ^ (l15 & 7);
                short8 vf = *(const short8*)&Vs[bi][(dt * 16 + l15) * 64 + slot * 8];
                t = __builtin_amdgcn_mfma_f32_16x16x32_bf16(__builtin_bit_cast(short8, aw[kh]), vf, t, 0, 0, 0);
            }
            o[dt] = t;
        }
        __builtin_amdgcn_s_setprio(0);
    }
    float li = 1.0f / l;
    float lr[4];
#pragma unroll
    for (int r = 0; r < 4; ++r) lr[r] = __shfl(li, quad * 4 + r);
    short* Oo = O + ((size_t)b * SEQ + qt * 128 + wave * 16 + quad * 4) * DIM + h * HD + l15;
#pragma unroll
    for (int r = 0; r < 4; ++r)
#pragma unroll
        for (int dt = 0; dt < 4; ++dt)
            Oo[(size_t)r * DIM + dt * 16] = fbf(o[dt][r] * lr[r]);
}

// ---------------------------------------------------------------------------
extern "C" void kernel_launch(void* const* d_in, const int* in_sizes, int n_in,
                              void* d_out, int out_size, void* d_ws, size_t ws_size,
                              hipStream_t stream) {
    const float* X    = (const float*)d_in[0];
    const float* cosT = (const float*)d_in[2];
    const float* sinT = (const float*)d_in[3];
    const float* Wq   = (const float*)d_in[4];
    const float* Wk   = (const float*)d_in[5];
    const float* Wv   = (const float*)d_in[6];
    const float* Wo   = (const float*)d_in[7];

    char* ws = (char*)d_ws;
    short* Xb    = (short*)(ws);                  // 16.8 MB; ATTb aliases after QKV gemm
    short* ATTb  = Xb;
    short* WQKVb = (short*)(ws + 16777216);       // 12.6 MB
    short* Wob   = (short*)(ws + 29360128);       // 8.4 MB
    short* Qbb   = (short*)(ws + 37748736);       // 16.8 MB
    short* Kbb   = (short*)(ws + 54525952);       // 4.2 MB (B*S*KVDIM bf16)
    short* VTb   = (short*)(ws + 58720256);       // 4.2 MB (B*NKV*HD*SEQ bf16)

    const int M = BSZ * SEQ;

    prep<<<dim3(18432), dim3(256), 0, stream>>>(X, Wq, Wk, Wv, Wo, Xb, WQKVb, Wob);
    gemm_qkv<<<dim3(192), dim3(512), 0, stream>>>(Xb, WQKVb, cosT, sinT, Qbb, Kbb, VTb);
    flash4<<<dim3(1024), dim3(512), 0, stream>>>(Qbb, Kbb, VTb, ATTb);
    gemm_bf16<<<dim3(256), dim3(512), 0, stream>>>(ATTb, Wob, (float*)d_out, M, DIM, DIM);
}